// Round 7
// baseline (8197.315 us; speedup 1.0000x reference)
//
#include <hip/hip_runtime.h>
#include <hip/hip_bf16.h>

// dims fixed by the problem
#define S_LEN 512
#define B_SZ  32
#define H_DIM 512
#define KC    1024   // 2H

typedef __attribute__((ext_vector_type(8)))  short  short8;   // bf16x8
typedef __attribute__((ext_vector_type(4)))  float  f32x4;
typedef __attribute__((ext_vector_type(2)))  float  f32x2;

static __device__ __forceinline__ unsigned short f2bf(float f){
  unsigned u = __float_as_uint(f);
  u += 0x7fffu + ((u >> 16) & 1u);          // RNE
  return (unsigned short)(u >> 16);
}
static __device__ __forceinline__ short8 cvt8(float4 a, float4 b){
  short8 r;
  r[0]=(short)f2bf(a.x); r[1]=(short)f2bf(a.y); r[2]=(short)f2bf(a.z); r[3]=(short)f2bf(a.w);
  r[4]=(short)f2bf(b.x); r[5]=(short)f2bf(b.y); r[6]=(short)f2bf(b.z); r[7]=(short)f2bf(b.w);
  return r;
}
static __device__ __forceinline__ float sigf(float x){ return 1.0f/(1.0f+__expf(-x)); }
static __device__ __forceinline__ float tanh_(float x){
  float e = __expf(2.0f*x);
  return (e-1.0f)/(e+1.0f);
}

// ---- MALL-coherent (AGENT scope) accessors — round-2/6-proven semantics ----
static __device__ __forceinline__ void st_ag(float* p, float v){
  __hip_atomic_store(p, v, __ATOMIC_RELAXED, __HIP_MEMORY_SCOPE_AGENT);
}
static __device__ __forceinline__ float ld_ag(const float* p){
  return __hip_atomic_load((float*)p, __ATOMIC_RELAXED, __HIP_MEMORY_SCOPE_AGENT);
}

// ------------------- gather / conversion kernels -------------------
__global__ __launch_bounds__(256) void k_gather_emb(const int* __restrict__ src,
    const float* __restrict__ Wemb, unsigned short* __restrict__ embB){
  int gid = blockIdx.x*256 + threadIdx.x;
  int row = gid >> 6;
  int k   = (gid & 63) * 8;
  int idx = src[row];
  const float* p = Wemb + (size_t)idx*H_DIM + k;
  float4 a = *(const float4*)p;
  float4 b = *(const float4*)(p+4);
  *(short8*)(embB + (size_t)gid*8) = cvt8(a,b);
}

__global__ __launch_bounds__(256) void k_perm_wr(const float* __restrict__ W,
    unsigned short* __restrict__ out){
  int gid = blockIdx.x*256 + threadIdx.x;
  int n = gid >> 6;
  int k = (gid & 63)*8;
  int j = (n&3)*512 + (n>>2);
  const float* p = W + (size_t)j*512 + k;
  float4 a = *(const float4*)p;
  float4 b = *(const float4*)(p+4);
  *(short8*)(out + (size_t)gid*8) = cvt8(a,b);
}

__global__ __launch_bounds__(256) void k_perm_wihw(const float* __restrict__ W,
    unsigned short* __restrict__ out){
  int gid = blockIdx.x*256 + threadIdx.x;
  int n = gid >> 7;
  int k = (gid & 127)*8;
  int j = (n&3)*512 + (n>>2);
  const float* p = W + (size_t)j*KC + k;
  float4 a = *(const float4*)p;
  float4 b = *(const float4*)(p+4);
  *(short8*)(out + (size_t)gid*8) = cvt8(a,b);
}

__global__ __launch_bounds__(256) void k_wcT(const float* __restrict__ Wc,
    unsigned short* __restrict__ out){
  __shared__ float tile[64][65];
  int bx = blockIdx.x & 15, by = blockIdx.x >> 4;
  int c0 = bx*64, r0 = by*64;
  int row = threadIdx.x >> 2;
  int cp  = (threadIdx.x & 3)*16;
  for (int i=0;i<16;i+=4){
    float4 v = *(const float4*)&Wc[(size_t)(r0+row)*KC + c0 + cp + i];
    tile[row][cp+i+0]=v.x; tile[row][cp+i+1]=v.y; tile[row][cp+i+2]=v.z; tile[row][cp+i+3]=v.w;
  }
  __syncthreads();
  short8 s0, s1;
  for(int i=0;i<8;++i){
    s0[i]=(short)f2bf(tile[cp+i][row]);
    s1[i]=(short)f2bf(tile[cp+8+i][row]);
  }
  unsigned short* op = out + (size_t)(c0+row)*KC + r0 + cp;
  *(short8*)op = s0; *(short8*)(op+8) = s1;
}

__global__ __launch_bounds__(256) void k_bias_r(const float* __restrict__ bi,
    const float* __restrict__ bh, float* __restrict__ out){
  int n = blockIdx.x*256 + threadIdx.x;
  int j = (n&3)*512 + (n>>2);
  out[n] = bi[j] + bh[j];
}

__global__ __launch_bounds__(256) void k_bcomb(const float* __restrict__ Wihw,
    const float* __restrict__ bc, const float* __restrict__ bi,
    const float* __restrict__ bh, float* __restrict__ out){
  int n = blockIdx.x*256 + threadIdx.x;
  int j = (n&3)*512 + (n>>2);
  const float* wp = Wihw + (size_t)j*KC;
  float s = 0.f;
  for (int l=0;l<KC;l+=4){
    float4 w = *(const float4*)&wp[l];
    float4 c = *(const float4*)&bc[l];
    s += w.x*c.x + w.y*c.y + w.z*c.z + w.w*c.w;
  }
  out[n] = s + bi[j] + bh[j];
}

// ------------- bf16 MFMA GEMM  C = A·Bm^T  (A:[M][K], Bm:[N][bStride]) -----
// EPI=0: read-LSTM gate epilogue -> o_all f32 + o_allB bf16
// EPI=1: bf16 store (W_comb precompute)
// EPI=2: int16 store * 4096 (gates_o precompute), no bias
template<int EPI>
__global__ __launch_bounds__(256) void gemm_k(const unsigned short* __restrict__ A,
    const unsigned short* __restrict__ Bm, int K, int bStride, int bnCnt,
    const float* __restrict__ bias, float* __restrict__ outF,
    unsigned short* __restrict__ outB, short* __restrict__ outI, int outStride){
  __shared__ __align__(16) char smem[66560];
  unsigned short* As = (unsigned short*)smem;
  unsigned short* Bs = As + 128*72;
  float* epi = (float*)smem;
  const int tid = threadIdx.x, lane = tid & 63, w = tid >> 6;
  const int wr = w >> 1, wc = w & 1;
  const int bm = blockIdx.x / bnCnt, bn = blockIdx.x % bnCnt;
  f32x4 acc[4][4] = {};
  const size_t Abase = (size_t)bm*128*K;
  const size_t Bbase = (size_t)bn*128*bStride;
  for (int k0 = 0; k0 < K; k0 += 64){
    __syncthreads();
    #pragma unroll
    for (int i = 0; i < 4; ++i){
      int idx = tid + i*256;
      int row = idx >> 3, cb = (idx & 7)*8;
      *(short8*)&As[row*72 + cb] = *(const short8*)&A[Abase + (size_t)row*K + k0 + cb];
      *(short8*)&Bs[row*72 + cb] = *(const short8*)&Bm[Bbase + (size_t)row*bStride + k0 + cb];
    }
    __syncthreads();
    #pragma unroll
    for (int kk = 0; kk < 64; kk += 32){
      short8 af[4], bf[4];
      #pragma unroll
      for (int i=0;i<4;++i) af[i] = *(short8*)&As[(wr*64 + i*16 + (lane&15))*72 + kk + (lane>>4)*8];
      #pragma unroll
      for (int j=0;j<4;++j) bf[j] = *(short8*)&Bs[(wc*64 + j*16 + (lane&15))*72 + kk + (lane>>4)*8];
      #pragma unroll
      for (int i=0;i<4;++i)
        #pragma unroll
        for (int j=0;j<4;++j)
          acc[i][j] = __builtin_amdgcn_mfma_f32_16x16x32_bf16(af[i], bf[j], acc[i][j], 0,0,0);
    }
  }
  if (EPI == 0){
    float bj[4];
    #pragma unroll
    for (int j=0;j<4;++j) bj[j] = bias[bn*128 + wc*64 + j*16 + (lane&15)];
    __syncthreads();
    float* ep = epi + w*(64*65);
    #pragma unroll
    for (int i=0;i<4;++i)
      #pragma unroll
      for (int j=0;j<4;++j)
        #pragma unroll
        for (int r=0;r<4;++r)
          ep[(i*16 + (lane>>4)*4 + r)*65 + j*16 + (lane&15)] = acc[i][j][r] + bj[j];
    __syncthreads();
    int rg = bm*128 + wr*64 + lane;
    #pragma unroll
    for (int q=0;q<16;++q){
      float gi = ep[lane*65 + q*4+0];
      float gg = ep[lane*65 + q*4+2];
      float go = ep[lane*65 + q*4+3];
      float c = sigf(gi)*tanh_(gg);
      float h = sigf(go)*tanh_(c);
      int cg = bn*32 + wc*16 + q;
      outF[(size_t)rg*H_DIM + cg] = h;
      outB[(size_t)rg*H_DIM + cg] = f2bf(h);
    }
  } else if (EPI == 1){
    #pragma unroll
    for (int i=0;i<4;++i)
      #pragma unroll
      for (int j=0;j<4;++j)
        #pragma unroll
        for (int r=0;r<4;++r){
          int rg = bm*128 + wr*64 + i*16 + (lane>>4)*4 + r;
          int cg = bn*128 + wc*64 + j*16 + (lane&15);
          outB[(size_t)rg*outStride + cg] = f2bf(acc[i][j][r]);
        }
  } else {
    #pragma unroll
    for (int i=0;i<4;++i)
      #pragma unroll
      for (int j=0;j<4;++j)
        #pragma unroll
        for (int r=0;r<4;++r){
          int rg = bm*128 + wr*64 + i*16 + (lane>>4)*4 + r;
          int cg = bn*128 + wc*64 + j*16 + (lane&15);
          float v = acc[i][j][r] * 4096.0f;
          v = fminf(fmaxf(v, -32767.0f), 32767.0f);
          outI[(size_t)rg*outStride + cg] = (short)__float2int_rn(v);
        }
  }
}

// ------------------- persistent scan kernel (col-partition) -------------------
// Group = 8 blocks of one batch: b = bid>>3, c = bid&7. Block owns M[:, c*64..+64)
// in LDS for the whole scan. Per step: 2 reductions (d: 512 scores; gates: 2048
// cols), each via single-writer slots + a monotonic per-batch AGENT counter.
// Gates m-part weights (2048x64 bf16 = 256KB) pinned in VGPRs as MFMA B-frags;
// o-part precomputed (gates_o int16). No other W traffic in the loop.
__global__ __launch_bounds__(256,1) void scan_k(
    const int* __restrict__ src, const float* __restrict__ Wemb,
    const float* __restrict__ o_all, const unsigned short* __restrict__ Wcomb,
    const float* __restrict__ bcomb, const short* __restrict__ gatesO,
    float* __restrict__ dpart, float* __restrict__ gpart,
    float* __restrict__ out, int* __restrict__ cnts){
  __shared__ __align__(16) float M[512*66];   // 132 KB, pad 66: 2-way banks both passes
  __shared__ float z_lds[512];
  __shared__ float o_lds[64];
  __shared__ float h_lds[64];
  __shared__ float m_lds[64];
  __shared__ float part4[256];
  __shared__ float gg[256];
  __shared__ float red4[4];

  const int tid = threadIdx.x, lane = tid & 63, wv = tid >> 6;
  const int bid = blockIdx.x;
  const int c = bid & 7, b = bid >> 3;
  int* dcnt = cnts + b*64;
  int* gcnt = cnts + 2048 + b*64;
  float* dslot = dpart + ((size_t)b*8 + c)*512;
  float* gslot = gpart + ((size_t)b*8 + c)*2048;

  // ---- pin W m-part B-frags: wave wv covers col-tiles [wv*32, wv*32+32) ----
  short8 wf[64];     // [tile][kf]: 32 tiles x 2 K-frags = 256 VGPRs
  {
    const unsigned short* wbase = Wcomb + 512 + c*64 + (lane>>4)*8;
    #pragma unroll
    for (int i=0;i<32;++i){
      int n = (wv*32 + i)*16 + (lane&15);
      const unsigned short* wp = wbase + (size_t)n*KC;
      wf[i*2+0] = *(const short8*)(wp);
      wf[i*2+1] = *(const short8*)(wp + 32);
    }
  }

  // ---- init: M0 gather (col-slice), z=h=0 ----
  if (tid < 64){ h_lds[tid] = 0.f; }
  z_lds[tid] = 0.f; z_lds[tid+256] = 0.f;
  #pragma unroll
  for (int r=0;r<2;++r){
    int s = tid + r*256;
    int idx = src[s*B_SZ + b];
    const float* wp = Wemb + (size_t)idx*H_DIM + c*64;
    float* mp = &M[s*66];
    #pragma unroll
    for (int k=0;k<64;k+=4){
      float4 v = *(const float4*)&wp[k];
      *(f32x2*)&mp[k]   = (f32x2){v.x, v.y};
      *(f32x2*)&mp[k+2] = (f32x2){v.z, v.w};
    }
  }
  __syncthreads();

  for (int t=0; t<S_LEN; ++t){
    // ---- stage 1: o_t slice ----
    if (tid < 64) o_lds[tid] = o_all[((size_t)t*B_SZ + b)*H_DIM + c*64 + tid];
    __syncthreads();

    // ---- stage 2: sweep rows: apply (z_{t-1},h_{t-1}) update, d = M·o_t ----
    #pragma unroll
    for (int r=0;r<2;++r){
      int s = tid + r*256;
      float zp = z_lds[s];
      float* mp = &M[s*66];
      float dd = 0.f;
      #pragma unroll
      for (int k=0;k<64;k+=2){
        f32x2 v = *(f32x2*)&mp[k];
        f32x2 h2 = *(f32x2*)&h_lds[k];
        f32x2 o2 = *(f32x2*)&o_lds[k];
        v[0] += zp*(h2[0]-v[0]); v[1] += zp*(h2[1]-v[1]);
        *(f32x2*)&mp[k] = v;
        dd += v[0]*o2[0] + v[1]*o2[1];
      }
      st_ag(&dslot[s], dd);
    }

    // ---- stage 3: d-flag ----
    __syncthreads();
    asm volatile("s_waitcnt vmcnt(0)" ::: "memory");
    if (tid == 0){
      __hip_atomic_fetch_add(dcnt, 1, __ATOMIC_RELAXED, __HIP_MEMORY_SCOPE_AGENT);
      int tg = 8*(t+1);
      while (__hip_atomic_load(dcnt, __ATOMIC_RELAXED, __HIP_MEMORY_SCOPE_AGENT) < tg)
        __builtin_amdgcn_s_sleep(1);
    }
    __syncthreads();
    asm volatile("" ::: "memory");

    // ---- stage 4: score sum + softmax (identical across the 8 blocks) ----
    float sc0 = 0.f, sc1 = 0.f;
    #pragma unroll
    for (int c2=0;c2<8;++c2){
      const float* dp = dpart + ((size_t)b*8 + c2)*512;
      sc0 += ld_ag(&dp[tid]);
      sc1 += ld_ag(&dp[tid+256]);
    }
    float mx, sm;
    {
      float v = fmaxf(sc0, sc1);
      #pragma unroll
      for (int m2=32;m2>0;m2>>=1) v = fmaxf(v, __shfl_xor(v, m2));
      __syncthreads();
      if (lane==0) red4[wv] = v;
      __syncthreads();
      mx = fmaxf(fmaxf(red4[0],red4[1]), fmaxf(red4[2],red4[3]));
    }
    float ex0 = __expf(sc0 - mx), ex1 = __expf(sc1 - mx);
    {
      float v = ex0 + ex1;
      #pragma unroll
      for (int m2=32;m2>0;m2>>=1) v += __shfl_xor(v, m2);
      __syncthreads();
      if (lane==0) red4[wv] = v;
      __syncthreads();
      sm = (red4[0]+red4[1]) + (red4[2]+red4[3]);
    }
    float inv = 1.f / sm;
    z_lds[tid] = ex0*inv;        // z_t
    z_lds[tid+256] = ex1*inv;
    __syncthreads();

    // ---- stage 5: m_c = sum_s z_t[s] * M[s, slice] (column sums) ----
    {
      int col = tid & 63;
      int s0 = wv*128;
      float mp = 0.f;
      #pragma unroll 8
      for (int s2=0;s2<128;++s2)
        mp += z_lds[s0+s2]*M[(s0+s2)*66 + col];
      part4[wv*64 + col] = mp;
    }
    __syncthreads();
    if (tid < 64)
      m_lds[tid] = (part4[tid]+part4[64+tid]) + (part4[128+tid]+part4[192+tid]);
    __syncthreads();

    // ---- stage 6: partial gates = W_m-slice · m_c  (pinned-VGPR MFMA) ----
    {
      short8 a0 = {0,0,0,0,0,0,0,0}, a1 = a0;
      if ((lane & 15) == 0){
        int kq = (lane>>4)*8;
        #pragma unroll
        for (int j=0;j<8;++j){
          a0[j] = (short)f2bf(m_lds[kq+j]);
          a1[j] = (short)f2bf(m_lds[32+kq+j]);
        }
      }
      #pragma unroll
      for (int i=0;i<32;++i){
        f32x4 acc = {0.f,0.f,0.f,0.f};
        acc = __builtin_amdgcn_mfma_f32_16x16x32_bf16(a0, wf[i*2+0], acc, 0,0,0);
        acc = __builtin_amdgcn_mfma_f32_16x16x32_bf16(a1, wf[i*2+1], acc, 0,0,0);
        if (lane < 16)
          st_ag(&gslot[wv*512 + i*16 + lane], acc[0]);   // C row 0 = valid batch row
      }
    }

    // ---- stage 7: g-flag ----
    __syncthreads();
    asm volatile("s_waitcnt vmcnt(0)" ::: "memory");
    if (tid == 0){
      __hip_atomic_fetch_add(gcnt, 1, __ATOMIC_RELAXED, __HIP_MEMORY_SCOPE_AGENT);
      int tg = 8*(t+1);
      while (__hip_atomic_load(gcnt, __ATOMIC_RELAXED, __HIP_MEMORY_SCOPE_AGENT) < tg)
        __builtin_amdgcn_s_sleep(1);
    }
    __syncthreads();
    asm volatile("" ::: "memory");

    // ---- stage 8: assemble own 256 gate cols -> h slice ----
    {
      int col = c*256 + tid;
      float gv = bcomb[col]
               + (float)gatesO[((size_t)t*B_SZ + b)*2048 + col] * (1.0f/4096.0f);
      #pragma unroll
      for (int c2=0;c2<8;++c2)
        gv += ld_ag(&gpart[((size_t)b*8 + c2)*2048 + col]);
      gg[tid] = gv;
    }
    __syncthreads();
    if (tid < 64){
      float gi = gg[tid*4+0];
      float gG = gg[tid*4+2];
      float go = gg[tid*4+3];
      float ccv = sigf(gi)*tanh_(gG);
      float hh  = sigf(go)*tanh_(ccv);
      h_lds[tid] = hh;                                   // h_t slice for next sweep
      int hq = c*64 + tid;
      out[((size_t)t*B_SZ + b)*H_DIM + hq] = hh;
      if (t == S_LEN-1){
        out[(size_t)S_LEN*B_SZ*H_DIM + (size_t)b*H_DIM + hq] = hh;
        out[(size_t)S_LEN*B_SZ*H_DIM + (size_t)B_SZ*H_DIM + (size_t)b*H_DIM + hq] = ccv;
      }
    }
    __syncthreads();
  }
}

// ------------------- host launch -------------------
extern "C" void kernel_launch(void* const* d_in, const int* in_sizes, int n_in,
                              void* d_out, int out_size, void* d_ws, size_t ws_size,
                              hipStream_t stream){
  const int*   src   = (const int*)  d_in[0];
  const float* Wemb  = (const float*)d_in[1];
  const float* Wihr  = (const float*)d_in[2];
  const float* bihr  = (const float*)d_in[3];
  const float* bhhr  = (const float*)d_in[4];
  const float* Wc    = (const float*)d_in[5];
  const float* bc    = (const float*)d_in[6];
  const float* Wihw  = (const float*)d_in[7];
  const float* bihw  = (const float*)d_in[8];
  const float* bhhw  = (const float*)d_in[9];
  float* out = (float*)d_out;

  char* ws = (char*)d_ws;
  size_t off = 0;
  auto alloc = [&](size_t bytes)->char*{
    char* p = ws + off; off += (bytes + 255) & ~(size_t)255; return p;
  };
  unsigned short* embB  = (unsigned short*)alloc((size_t)16384*512*2);   // 16 MB
  float*          o_all = (float*)         alloc((size_t)16384*512*4);   // 32 MB
  unsigned short* o_allB= (unsigned short*)alloc((size_t)16384*512*2);   // 16 MB
  unsigned short* WrP   = (unsigned short*)alloc((size_t)2048*512*2);    //  2 MB
  unsigned short* WiwP  = (unsigned short*)alloc((size_t)2048*1024*2);   //  4 MB
  unsigned short* WcT   = (unsigned short*)alloc((size_t)1024*1024*2);   //  2 MB
  unsigned short* Wcomb = (unsigned short*)alloc((size_t)2048*1024*2);   //  4 MB
  float*          bperm = (float*)alloc(2048*4);
  float*          bcomb = (float*)alloc(2048*4);
  short*          gatesO= (short*)alloc((size_t)16384*2048*2);           // 64 MB
  float*          dpart = (float*)alloc((size_t)32*8*512*4);             // 512 KB
  float*          gpart = (float*)alloc((size_t)32*8*2048*4);            //  2 MB
  int*            cnts  = (int*)  alloc(16384);

  hipMemsetAsync(cnts, 0, 16384, stream);
  k_gather_emb<<<4096,256,0,stream>>>(src, Wemb, embB);
  k_perm_wr  <<<512, 256,0,stream>>>(Wihr, WrP);
  k_perm_wihw<<<1024,256,0,stream>>>(Wihw, WiwP);
  k_wcT      <<<256, 256,0,stream>>>(Wc, WcT);
  k_bias_r   <<<8,   256,0,stream>>>(bihr, bhhr, bperm);
  k_bcomb    <<<8,   256,0,stream>>>(Wihw, bc, bihw, bhhw, bcomb);
  // read-LSTM: o_all (f32) + o_allB (bf16)
  gemm_k<0><<<2048,256,0,stream>>>(embB, WrP, 512, 512, 16, bperm, o_all, o_allB, nullptr, H_DIM);
  // W_comb = (perm W_ih_w) @ W_c
  gemm_k<1><<<128,256,0,stream>>>(WiwP, WcT, 1024, 1024, 8, nullptr, nullptr, Wcomb, nullptr, 1024);
  // gates_o = o_all · W_o^T (K=512 = first half of Wcomb cols), int16 x4096
  gemm_k<2><<<2048,256,0,stream>>>(o_allB, Wcomb, 512, 1024, 16, nullptr, nullptr, nullptr, gatesO, 2048);
  // persistent scan: 256 blocks = 32 batches x 8 col-slices
  scan_k<<<256,256,0,stream>>>(src, Wemb, o_all, Wcomb, bcomb, gatesO,
                               dpart, gpart, out, cnts);
}

// Round 8
// 6176.955 us; speedup vs baseline: 1.3271x; 1.3271x over previous
//
#include <hip/hip_runtime.h>
#include <hip/hip_bf16.h>

// dims fixed by the problem
#define S_LEN 512
#define B_SZ  32
#define H_DIM 512
#define KC    1024   // 2H

typedef __attribute__((ext_vector_type(8)))  short  short8;   // bf16x8
typedef __attribute__((ext_vector_type(4)))  float  f32x4;
typedef __attribute__((ext_vector_type(2)))  float  f32x2;

static __device__ __forceinline__ unsigned short f2bf(float f){
  unsigned u = __float_as_uint(f);
  u += 0x7fffu + ((u >> 16) & 1u);          // RNE
  return (unsigned short)(u >> 16);
}
static __device__ __forceinline__ short8 cvt8(float4 a, float4 b){
  short8 r;
  r[0]=(short)f2bf(a.x); r[1]=(short)f2bf(a.y); r[2]=(short)f2bf(a.z); r[3]=(short)f2bf(a.w);
  r[4]=(short)f2bf(b.x); r[5]=(short)f2bf(b.y); r[6]=(short)f2bf(b.z); r[7]=(short)f2bf(b.w);
  return r;
}
static __device__ __forceinline__ float sigf(float x){ return 1.0f/(1.0f+__expf(-x)); }
static __device__ __forceinline__ float tanh_(float x){
  float e = __expf(2.0f*x);
  return (e-1.0f)/(e+1.0f);
}

// ------------------- gather / conversion kernels -------------------
__global__ __launch_bounds__(256) void k_gather_emb(const int* __restrict__ src,
    const float* __restrict__ Wemb, unsigned short* __restrict__ embB){
  int gid = blockIdx.x*256 + threadIdx.x;
  int row = gid >> 6;
  int k   = (gid & 63) * 8;
  int idx = src[row];
  const float* p = Wemb + (size_t)idx*H_DIM + k;
  float4 a = *(const float4*)p;
  float4 b = *(const float4*)(p+4);
  *(short8*)(embB + (size_t)gid*8) = cvt8(a,b);
}

__global__ __launch_bounds__(256) void k_perm_wr(const float* __restrict__ W,
    unsigned short* __restrict__ out){
  int gid = blockIdx.x*256 + threadIdx.x;
  int n = gid >> 6;
  int k = (gid & 63)*8;
  int j = (n&3)*512 + (n>>2);
  const float* p = W + (size_t)j*512 + k;
  float4 a = *(const float4*)p;
  float4 b = *(const float4*)(p+4);
  *(short8*)(out + (size_t)gid*8) = cvt8(a,b);
}

__global__ __launch_bounds__(256) void k_perm_wihw(const float* __restrict__ W,
    unsigned short* __restrict__ out){
  int gid = blockIdx.x*256 + threadIdx.x;
  int n = gid >> 7;
  int k = (gid & 127)*8;
  int j = (n&3)*512 + (n>>2);
  const float* p = W + (size_t)j*KC + k;
  float4 a = *(const float4*)p;
  float4 b = *(const float4*)(p+4);
  *(short8*)(out + (size_t)gid*8) = cvt8(a,b);
}

__global__ __launch_bounds__(256) void k_wcT(const float* __restrict__ Wc,
    unsigned short* __restrict__ out){
  __shared__ float tile[64][65];
  int bx = blockIdx.x & 15, by = blockIdx.x >> 4;
  int c0 = bx*64, r0 = by*64;
  int row = threadIdx.x >> 2;
  int cp  = (threadIdx.x & 3)*16;
  for (int i=0;i<16;i+=4){
    float4 v = *(const float4*)&Wc[(size_t)(r0+row)*KC + c0 + cp + i];
    tile[row][cp+i+0]=v.x; tile[row][cp+i+1]=v.y; tile[row][cp+i+2]=v.z; tile[row][cp+i+3]=v.w;
  }
  __syncthreads();
  short8 s0, s1;
  for(int i=0;i<8;++i){
    s0[i]=(short)f2bf(tile[cp+i][row]);
    s1[i]=(short)f2bf(tile[cp+8+i][row]);
  }
  unsigned short* op = out + (size_t)(c0+row)*KC + r0 + cp;
  *(short8*)op = s0; *(short8*)(op+8) = s1;
}

__global__ __launch_bounds__(256) void k_bias_r(const float* __restrict__ bi,
    const float* __restrict__ bh, float* __restrict__ out){
  int n = blockIdx.x*256 + threadIdx.x;
  int j = (n&3)*512 + (n>>2);
  out[n] = bi[j] + bh[j];
}

__global__ __launch_bounds__(256) void k_bcomb(const float* __restrict__ Wihw,
    const float* __restrict__ bc, const float* __restrict__ bi,
    const float* __restrict__ bh, float* __restrict__ out){
  int n = blockIdx.x*256 + threadIdx.x;
  int j = (n&3)*512 + (n>>2);
  const float* wp = Wihw + (size_t)j*KC;
  float s = 0.f;
  for (int l=0;l<KC;l+=4){
    float4 w = *(const float4*)&wp[l];
    float4 c = *(const float4*)&bc[l];
    s += w.x*c.x + w.y*c.y + w.z*c.z + w.w*c.w;
  }
  out[n] = s + bi[j] + bh[j];
}

// ------------- bf16 MFMA GEMM  C = A·Bm^T  (A:[M][K], Bm:[N][bStride]) -----
template<int EPI>
__global__ __launch_bounds__(256) void gemm_k(const unsigned short* __restrict__ A,
    const unsigned short* __restrict__ Bm, int K, int bStride, int bnCnt,
    const float* __restrict__ bias, float* __restrict__ outF,
    unsigned short* __restrict__ outB, short* __restrict__ outI, int outStride){
  __shared__ __align__(16) char smem[66560];
  unsigned short* As = (unsigned short*)smem;
  unsigned short* Bs = As + 128*72;
  float* epi = (float*)smem;
  const int tid = threadIdx.x, lane = tid & 63, w = tid >> 6;
  const int wr = w >> 1, wc = w & 1;
  const int bm = blockIdx.x / bnCnt, bn = blockIdx.x % bnCnt;
  f32x4 acc[4][4] = {};
  const size_t Abase = (size_t)bm*128*K;
  const size_t Bbase = (size_t)bn*128*bStride;
  for (int k0 = 0; k0 < K; k0 += 64){
    __syncthreads();
    #pragma unroll
    for (int i = 0; i < 4; ++i){
      int idx = tid + i*256;
      int row = idx >> 3, cb = (idx & 7)*8;
      *(short8*)&As[row*72 + cb] = *(const short8*)&A[Abase + (size_t)row*K + k0 + cb];
      *(short8*)&Bs[row*72 + cb] = *(const short8*)&Bm[Bbase + (size_t)row*bStride + k0 + cb];
    }
    __syncthreads();
    #pragma unroll
    for (int kk = 0; kk < 64; kk += 32){
      short8 af[4], bf[4];
      #pragma unroll
      for (int i=0;i<4;++i) af[i] = *(short8*)&As[(wr*64 + i*16 + (lane&15))*72 + kk + (lane>>4)*8];
      #pragma unroll
      for (int j=0;j<4;++j) bf[j] = *(short8*)&Bs[(wc*64 + j*16 + (lane&15))*72 + kk + (lane>>4)*8];
      #pragma unroll
      for (int i=0;i<4;++i)
        #pragma unroll
        for (int j=0;j<4;++j)
          acc[i][j] = __builtin_amdgcn_mfma_f32_16x16x32_bf16(af[i], bf[j], acc[i][j], 0,0,0);
    }
  }
  if (EPI == 0){
    float bj[4];
    #pragma unroll
    for (int j=0;j<4;++j) bj[j] = bias[bn*128 + wc*64 + j*16 + (lane&15)];
    __syncthreads();
    float* ep = epi + w*(64*65);
    #pragma unroll
    for (int i=0;i<4;++i)
      #pragma unroll
      for (int j=0;j<4;++j)
        #pragma unroll
        for (int r=0;r<4;++r)
          ep[(i*16 + (lane>>4)*4 + r)*65 + j*16 + (lane&15)] = acc[i][j][r] + bj[j];
    __syncthreads();
    int rg = bm*128 + wr*64 + lane;
    #pragma unroll
    for (int q=0;q<16;++q){
      float gi = ep[lane*65 + q*4+0];
      float gg = ep[lane*65 + q*4+2];
      float go = ep[lane*65 + q*4+3];
      float c = sigf(gi)*tanh_(gg);
      float h = sigf(go)*tanh_(c);
      int cg = bn*32 + wc*16 + q;
      outF[(size_t)rg*H_DIM + cg] = h;
      outB[(size_t)rg*H_DIM + cg] = f2bf(h);
    }
  } else if (EPI == 1){
    #pragma unroll
    for (int i=0;i<4;++i)
      #pragma unroll
      for (int j=0;j<4;++j)
        #pragma unroll
        for (int r=0;r<4;++r){
          int rg = bm*128 + wr*64 + i*16 + (lane>>4)*4 + r;
          int cg = bn*128 + wc*64 + j*16 + (lane&15);
          outB[(size_t)rg*outStride + cg] = f2bf(acc[i][j][r]);
        }
  } else {
    #pragma unroll
    for (int i=0;i<4;++i)
      #pragma unroll
      for (int j=0;j<4;++j)
        #pragma unroll
        for (int r=0;r<4;++r){
          int rg = bm*128 + wr*64 + i*16 + (lane>>4)*4 + r;
          int cg = bn*128 + wc*64 + j*16 + (lane&15);
          float v = acc[i][j][r] * 4096.0f;
          v = fminf(fmaxf(v, -32767.0f), 32767.0f);
          outI[(size_t)rg*outStride + cg] = (short)__float2int_rn(v);
        }
  }
}

// ------------------- persistent scan kernel (col-partition, wide MALL xfer) --
// Group = 8 blocks of one batch (b = bid>>3, c = bid&7); block owns M[:, c*64..+64).
// ALL cross-block data moves as wide dwordx2/x4 with sc0 sc1 (L1/L2-bypass,
// MALL-coherent, TA-coalesced), staged via LDS so chunks are contiguous.
// Flags: per-batch monotonic AGENT counters (round-6/7-proven).
__global__ __launch_bounds__(256,1) void scan_k(
    const int* __restrict__ src, const float* __restrict__ Wemb,
    const float* __restrict__ o_all, const unsigned short* __restrict__ Wcomb,
    const float* __restrict__ bcomb, const short* __restrict__ gatesO,
    float* __restrict__ dpart, float* __restrict__ gpart,
    float* __restrict__ out, int* __restrict__ cnts){
  __shared__ __align__(16) float M[512*66];   // 132 KB, pad 66
  __shared__ __align__(16) float ubuf[2048];  // 8 KB: d_stage | part4 | gstage | gsum
  __shared__ float z_lds[512];
  __shared__ float o_lds[64];
  __shared__ float h_lds[64];
  __shared__ float m_lds[64];
  __shared__ float gg[256];
  __shared__ float red4[4];

  const int tid = threadIdx.x, lane = tid & 63, wv = tid >> 6;
  const int bid = blockIdx.x;
  const int c = bid & 7, b = bid >> 3;
  int* dcnt = cnts + b*64;
  int* gcnt = cnts + 2048 + b*64;
  float* dslot = dpart + ((size_t)b*8 + c)*512;
  float* gslot = gpart + ((size_t)b*8 + c)*2048;

  // ---- pin W m-part B-frags: wave wv covers col-tiles [wv*32, wv*32+32) ----
  short8 wf[64];     // [tile][kf]: 32 tiles x 2 K-frags
  {
    const unsigned short* wbase = Wcomb + 512 + c*64 + (lane>>4)*8;
    #pragma unroll
    for (int i=0;i<32;++i){
      int n = (wv*32 + i)*16 + (lane&15);
      const unsigned short* wp = wbase + (size_t)n*KC;
      wf[i*2+0] = *(const short8*)(wp);
      wf[i*2+1] = *(const short8*)(wp + 32);
    }
  }

  // ---- init: M0 gather (col-slice), z=h=0 ----
  if (tid < 64){ h_lds[tid] = 0.f; }
  z_lds[tid] = 0.f; z_lds[tid+256] = 0.f;
  #pragma unroll
  for (int r=0;r<2;++r){
    int s = tid + r*256;
    int idx = src[s*B_SZ + b];
    const float* wp = Wemb + (size_t)idx*H_DIM + c*64;
    float* mp = &M[s*66];
    #pragma unroll
    for (int k=0;k<64;k+=4){
      float4 v = *(const float4*)&wp[k];
      *(f32x2*)&mp[k]   = (f32x2){v.x, v.y};
      *(f32x2*)&mp[k+2] = (f32x2){v.z, v.w};
    }
  }
  // prefetch step-0 inputs
  float o_pref = 0.f;
  if (tid < 64) o_pref = o_all[(size_t)b*H_DIM + c*64 + tid];
  float gO_pref = (float)gatesO[(size_t)b*2048 + c*256 + tid] * (1.0f/4096.0f);
  __syncthreads();

  for (int t=0; t<S_LEN; ++t){
    // ---- stage 1: o_t slice from prefetch ----
    if (tid < 64) o_lds[tid] = o_pref;
    float gO = gO_pref;
    __syncthreads();

    // ---- stage 2: sweep rows: apply (z_{t-1},h_{t-1}) update, d = M·o_t ----
    #pragma unroll
    for (int r=0;r<2;++r){
      int s = tid + r*256;
      float zp = z_lds[s];
      float* mp = &M[s*66];
      float dd = 0.f;
      #pragma unroll
      for (int k=0;k<64;k+=2){
        f32x2 v = *(f32x2*)&mp[k];
        f32x2 h2 = *(f32x2*)&h_lds[k];
        f32x2 o2 = *(f32x2*)&o_lds[k];
        v[0] += zp*(h2[0]-v[0]); v[1] += zp*(h2[1]-v[1]);
        *(f32x2*)&mp[k] = v;
        dd += v[0]*o2[0] + v[1]*o2[1];
      }
      ubuf[s] = dd;                         // d_stage
    }
    __syncthreads();
    // wide coherent store of own d-partial (contiguous 8B per thread)
    {
      f32x2 v = *(f32x2*)&ubuf[2*tid];
      float* p = dslot + 2*tid;
      asm volatile("global_store_dwordx2 %0, %1, off sc0 sc1" :: "v"(p), "v"(v) : "memory");
    }

    // ---- stage 3: d-flag ----
    asm volatile("s_waitcnt vmcnt(0)" ::: "memory");
    if (tid == 0){
      __hip_atomic_fetch_add(dcnt, 1, __ATOMIC_RELAXED, __HIP_MEMORY_SCOPE_AGENT);
      int tg = 8*(t+1);
      while (__hip_atomic_load(dcnt, __ATOMIC_RELAXED, __HIP_MEMORY_SCOPE_AGENT) < tg)
        __builtin_amdgcn_s_sleep(1);
    }
    __syncthreads();
    asm volatile("" ::: "memory");

    // ---- stage 4: wide gather of 8 d-partials (rows 2tid, 2tid+1) + softmax ----
    float d0, d1;
    {
      const float* p0 = dpart + (size_t)b*8*512 + 2*tid;
      f32x2 a0,a1,a2,a3,a4,a5,a6,a7;
      asm volatile(
        "global_load_dwordx2 %0, %8, off sc0 sc1\n\t"
        "global_load_dwordx2 %1, %9, off sc0 sc1\n\t"
        "global_load_dwordx2 %2, %10, off sc0 sc1\n\t"
        "global_load_dwordx2 %3, %11, off sc0 sc1\n\t"
        "global_load_dwordx2 %4, %12, off sc0 sc1\n\t"
        "global_load_dwordx2 %5, %13, off sc0 sc1\n\t"
        "global_load_dwordx2 %6, %14, off sc0 sc1\n\t"
        "global_load_dwordx2 %7, %15, off sc0 sc1\n\t"
        "s_waitcnt vmcnt(0)"
        : "=&v"(a0),"=&v"(a1),"=&v"(a2),"=&v"(a3),
          "=&v"(a4),"=&v"(a5),"=&v"(a6),"=&v"(a7)
        : "v"(p0), "v"(p0+512), "v"(p0+1024), "v"(p0+1536),
          "v"(p0+2048), "v"(p0+2560), "v"(p0+3072), "v"(p0+3584)
        : "memory");
      d0 = ((a0[0]+a1[0])+(a2[0]+a3[0])) + ((a4[0]+a5[0])+(a6[0]+a7[0]));
      d1 = ((a0[1]+a1[1])+(a2[1]+a3[1])) + ((a4[1]+a5[1])+(a6[1]+a7[1]));
    }
    float mx, sm;
    {
      float v = fmaxf(d0, d1);
      #pragma unroll
      for (int m2=32;m2>0;m2>>=1) v = fmaxf(v, __shfl_xor(v, m2));
      __syncthreads();
      if (lane==0) red4[wv] = v;
      __syncthreads();
      mx = fmaxf(fmaxf(red4[0],red4[1]), fmaxf(red4[2],red4[3]));
    }
    float ex0 = __expf(d0 - mx), ex1 = __expf(d1 - mx);
    {
      float v = ex0 + ex1;
      #pragma unroll
      for (int m2=32;m2>0;m2>>=1) v += __shfl_xor(v, m2);
      __syncthreads();
      if (lane==0) red4[wv] = v;
      __syncthreads();
      sm = (red4[0]+red4[1]) + (red4[2]+red4[3]);
    }
    float inv = 1.f / sm;
    z_lds[2*tid]   = ex0*inv;        // z_t
    z_lds[2*tid+1] = ex1*inv;
    // prefetch next step's o slice + gatesO value (consumed next iteration /
    // stage 8; drained by stage-7 vmcnt after ~2-3us of slack)
    {
      int tn = (t < S_LEN-1) ? t+1 : t;
      if (tid < 64) o_pref = o_all[((size_t)tn*B_SZ + b)*H_DIM + c*64 + tid];
      gO_pref = (float)gatesO[((size_t)tn*B_SZ + b)*2048 + c*256 + tid] * (1.0f/4096.0f);
    }
    __syncthreads();

    // ---- stage 5: m_c = sum_s z_t[s] * M[s, slice] (column sums) ----
    {
      float* part4 = ubuf;                  // [4][64]
      int col = tid & 63;
      int s0 = wv*128;
      float mp = 0.f;
      #pragma unroll 8
      for (int s2=0;s2<128;++s2)
        mp += z_lds[s0+s2]*M[(s0+s2)*66 + col];
      part4[wv*64 + col] = mp;
    }
    __syncthreads();
    if (tid < 64)
      m_lds[tid] = (ubuf[tid]+ubuf[64+tid]) + (ubuf[128+tid]+ubuf[192+tid]);
    __syncthreads();

    // ---- stage 6: partial gates = W_m-slice · m_c (pinned-VGPR MFMA) ----
    {
      short8 a0 = {0,0,0,0,0,0,0,0}, a1 = a0;
      if ((lane & 15) == 0){
        int kq = (lane>>4)*8;
        #pragma unroll
        for (int j=0;j<8;++j){
          a0[j] = (short)f2bf(m_lds[kq+j]);
          a1[j] = (short)f2bf(m_lds[32+kq+j]);
        }
      }
      float* gstage = ubuf;                 // [2048]
      #pragma unroll
      for (int i=0;i<32;++i){
        f32x4 acc = {0.f,0.f,0.f,0.f};
        acc = __builtin_amdgcn_mfma_f32_16x16x32_bf16(a0, wf[i*2+0], acc, 0,0,0);
        acc = __builtin_amdgcn_mfma_f32_16x16x32_bf16(a1, wf[i*2+1], acc, 0,0,0);
        if (lane < 16) gstage[wv*512 + i*16 + lane] = acc[0];
      }
    }
    __syncthreads();
    // wide coherent store of own gate-partial (32B per thread)
    {
      f32x4 g0 = *(f32x4*)&ubuf[8*tid];
      f32x4 g1 = *(f32x4*)&ubuf[8*tid+4];
      float* p = gslot + 8*tid;
      asm volatile(
        "global_store_dwordx4 %0, %2, off sc0 sc1\n\t"
        "global_store_dwordx4 %1, %3, off sc0 sc1"
        :: "v"(p), "v"(p+4), "v"(g0), "v"(g1) : "memory");
    }

    // ---- stage 7: g-flag ----
    asm volatile("s_waitcnt vmcnt(0)" ::: "memory");
    if (tid == 0){
      __hip_atomic_fetch_add(gcnt, 1, __ATOMIC_RELAXED, __HIP_MEMORY_SCOPE_AGENT);
      int tg = 8*(t+1);
      while (__hip_atomic_load(gcnt, __ATOMIC_RELAXED, __HIP_MEMORY_SCOPE_AGENT) < tg)
        __builtin_amdgcn_s_sleep(1);
    }
    __syncthreads();
    asm volatile("" ::: "memory");

    // ---- stage 8: wide gather of 8 gate-partials -> h slice ----
    {
      // thread t: slot tid>>5, cols c*256 + (tid&31)*8 .. +8
      const float* gp = gpart + ((size_t)b*8 + (tid>>5))*2048 + c*256 + (tid&31)*8;
      f32x4 f0, f1;
      asm volatile(
        "global_load_dwordx4 %0, %2, off sc0 sc1\n\t"
        "global_load_dwordx4 %1, %3, off sc0 sc1\n\t"
        "s_waitcnt vmcnt(0)"
        : "=&v"(f0), "=&v"(f1)
        : "v"(gp), "v"(gp+4) : "memory");
      float* gsum = ubuf;                   // [8][256]
      *(f32x4*)&gsum[(tid>>5)*256 + (tid&31)*8]     = f0;
      *(f32x4*)&gsum[(tid>>5)*256 + (tid&31)*8 + 4] = f1;
    }
    __syncthreads();
    {
      float gv = gO + bcomb[c*256 + tid];
      #pragma unroll
      for (int c2=0;c2<8;++c2) gv += ubuf[c2*256 + tid];
      gg[tid] = gv;
    }
    __syncthreads();
    if (tid < 64){
      float gi = gg[tid*4+0];
      float gG = gg[tid*4+2];
      float go = gg[tid*4+3];
      float ccv = sigf(gi)*tanh_(gG);
      float hh  = sigf(go)*tanh_(ccv);
      h_lds[tid] = hh;                      // h_t slice for next sweep
      int hq = c*64 + tid;
      out[((size_t)t*B_SZ + b)*H_DIM + hq] = hh;
      if (t == S_LEN-1){
        out[(size_t)S_LEN*B_SZ*H_DIM + (size_t)b*H_DIM + hq] = hh;
        out[(size_t)S_LEN*B_SZ*H_DIM + (size_t)B_SZ*H_DIM + (size_t)b*H_DIM + hq] = ccv;
      }
    }
    __syncthreads();
  }
}

// ------------------- host launch -------------------
extern "C" void kernel_launch(void* const* d_in, const int* in_sizes, int n_in,
                              void* d_out, int out_size, void* d_ws, size_t ws_size,
                              hipStream_t stream){
  const int*   src   = (const int*)  d_in[0];
  const float* Wemb  = (const float*)d_in[1];
  const float* Wihr  = (const float*)d_in[2];
  const float* bihr  = (const float*)d_in[3];
  const float* bhhr  = (const float*)d_in[4];
  const float* Wc    = (const float*)d_in[5];
  const float* bc    = (const float*)d_in[6];
  const float* Wihw  = (const float*)d_in[7];
  const float* bihw  = (const float*)d_in[8];
  const float* bhhw  = (const float*)d_in[9];
  float* out = (float*)d_out;

  char* ws = (char*)d_ws;
  size_t off = 0;
  auto alloc = [&](size_t bytes)->char*{
    char* p = ws + off; off += (bytes + 255) & ~(size_t)255; return p;
  };
  unsigned short* embB  = (unsigned short*)alloc((size_t)16384*512*2);   // 16 MB
  float*          o_all = (float*)         alloc((size_t)16384*512*4);   // 32 MB
  unsigned short* o_allB= (unsigned short*)alloc((size_t)16384*512*2);   // 16 MB
  unsigned short* WrP   = (unsigned short*)alloc((size_t)2048*512*2);    //  2 MB
  unsigned short* WiwP  = (unsigned short*)alloc((size_t)2048*1024*2);   //  4 MB
  unsigned short* WcT   = (unsigned short*)alloc((size_t)1024*1024*2);   //  2 MB
  unsigned short* Wcomb = (unsigned short*)alloc((size_t)2048*1024*2);   //  4 MB
  float*          bperm = (float*)alloc(2048*4);
  float*          bcomb = (float*)alloc(2048*4);
  short*          gatesO= (short*)alloc((size_t)16384*2048*2);           // 64 MB
  float*          dpart = (float*)alloc((size_t)32*8*512*4);             // 512 KB
  float*          gpart = (float*)alloc((size_t)32*8*2048*4);            //  2 MB
  int*            cnts  = (int*)  alloc(16384);

  hipMemsetAsync(cnts, 0, 16384, stream);
  k_gather_emb<<<4096,256,0,stream>>>(src, Wemb, embB);
  k_perm_wr  <<<512, 256,0,stream>>>(Wihr, WrP);
  k_perm_wihw<<<1024,256,0,stream>>>(Wihw, WiwP);
  k_wcT      <<<256, 256,0,stream>>>(Wc, WcT);
  k_bias_r   <<<8,   256,0,stream>>>(bihr, bhhr, bperm);
  k_bcomb    <<<8,   256,0,stream>>>(Wihw, bc, bihw, bhhw, bcomb);
  // read-LSTM: o_all (f32) + o_allB (bf16)
  gemm_k<0><<<2048,256,0,stream>>>(embB, WrP, 512, 512, 16, bperm, o_all, o_allB, nullptr, H_DIM);
  // W_comb = (perm W_ih_w) @ W_c
  gemm_k<1><<<128,256,0,stream>>>(WiwP, WcT, 1024, 1024, 8, nullptr, nullptr, Wcomb, nullptr, 1024);
  // gates_o = o_all · W_o^T (K=512 = first half of Wcomb cols), int16 x4096
  gemm_k<2><<<2048,256,0,stream>>>(o_allB, Wcomb, 512, 1024, 16, nullptr, nullptr, nullptr, gatesO, 2048);
  // persistent scan: 256 blocks = 32 batches x 8 col-slices
  scan_k<<<256,256,0,stream>>>(src, Wemb, o_all, Wcomb, bcomb, gatesO,
                               dpart, gpart, out, cnts);
}